// Round 13
// baseline (676.837 us; speedup 1.0000x reference)
//
#include <hip/hip_runtime.h>
#include <cstdint>
#include <cstddef>

#define DEV __device__ __forceinline__

typedef __attribute__((ext_vector_type(4))) float  f32x4;
typedef __attribute__((ext_vector_type(4))) float  float4v;
typedef __attribute__((ext_vector_type(8))) short  s16x8;
typedef __attribute__((ext_vector_type(4))) short  s16x4;

static constexpr int BB = 2, SS = 2048, HIDN = 1024, NHH = 16, FFN = 4096, DH = 64;
static constexpr int TWOK = 1024;                  // 2*K
static constexpr int HG = 8;                       // heads per attention group
static constexpr float ATT_SCALE = 0.07216878364870322f;  // 1/sqrt(3*DH)

// k_attn dynamic LDS: c2p rows (16 x 2056B) + mask + overlay
static constexpr int ROWB = 2056;
static constexpr int OFF_C2P = 0;                  // 32896
static constexpr int OFF_MSK = 32896;              // 8192
static constexpr int OFF_OVL = 41088;              // 34816 (Om overlay / Ps)
static constexpr int DYN_LDS = 75904;              // ~76KB -> 2 blocks/CU

DEV short f2bf(float f) {
  union { float f; uint32_t u; } v; v.f = f;
  uint32_t r = (v.u + 0x7fffu + ((v.u >> 16) & 1u)) >> 16;
  return (short)r;
}
DEV float bfu(unsigned short u) {
  union { uint32_t u; float f; } v; v.u = ((uint32_t)u) << 16; return v.f;
}
DEV int imin(int a, int b) { return a < b ? a : b; }
DEV int imax(int a, int b) { return a > b ? a : b; }

DEV void gl_lds16(const void* g, void* l) {
  __builtin_amdgcn_global_load_lds((const __attribute__((address_space(1))) void*)g,
                                   (__attribute__((address_space(3))) void*)l, 16, 0, 0);
}

#define MFMA16(a, b, c) __builtin_amdgcn_mfma_f32_16x16x32_bf16((a), (b), (c), 0, 0, 0)

// ---------------------------------------------------------------- transpose+cast (generic)
__global__ __launch_bounds__(256) void k_tcast(const float* __restrict__ in,
                                               short* __restrict__ out, int R, int C) {
  __shared__ float t[32][33];
  const int bx = blockIdx.x * 32, by = blockIdx.y * 32;
  const int tx = threadIdx.x & 31, ty = threadIdx.x >> 5;
#pragma unroll
  for (int r = ty; r < 32; r += 8) t[r][tx] = in[(size_t)(by + r) * C + bx + tx];
  __syncthreads();
#pragma unroll
  for (int c = ty; c < 32; c += 8) out[(size_t)(bx + c) * R + by + tx] = f2bf(t[tx][c]);
}

// ---------------------------------------------------------------- batched 1024x1024 transpose+cast
struct TCBatch { const float* in[5]; short* out[5]; };
__global__ __launch_bounds__(256) void k_tcast5(TCBatch tc) {
  __shared__ float t[32][33];
  const float* in = tc.in[blockIdx.z];
  short* out = tc.out[blockIdx.z];
  const int bx = blockIdx.x * 32, by = blockIdx.y * 32;
  const int tx = threadIdx.x & 31, ty = threadIdx.x >> 5;
#pragma unroll
  for (int r = ty; r < 32; r += 8) t[r][tx] = in[(size_t)(by + r) * 1024 + bx + tx];
  __syncthreads();
#pragma unroll
  for (int c = ty; c < 32; c += 8) out[(size_t)(bx + c) * 1024 + by + tx] = f2bf(t[tx][c]);
}

// ---------------------------------------------------------------- plain cast
__global__ __launch_bounds__(256) void k_cast(const float* __restrict__ in,
                                              short* __restrict__ out, int n4) {
  const int i = blockIdx.x * 256 + threadIdx.x;
  if (i < n4) {
    float4v v = ((const float4v*)in)[i];
    s16x4 o; o[0] = f2bf(v.x); o[1] = f2bf(v.y); o[2] = f2bf(v.z); o[3] = f2bf(v.w);
    ((s16x4*)out)[i] = o;
  }
}

// ---------------------------------------------------------------- layernorm
__global__ __launch_bounds__(256) void k_ln(const float* __restrict__ x,
                                            const float* __restrict__ gw,
                                            const float* __restrict__ bw,
                                            short* __restrict__ out) {
  const int row = blockIdx.x, t = threadIdx.x, lane = t & 63, wv = t >> 6;
  __shared__ float red[8];
  const float4v v = ((const float4v*)(x + (size_t)row * HIDN))[t];
  float s = v.x + v.y + v.z + v.w;
#pragma unroll
  for (int d = 1; d < 64; d <<= 1) s += __shfl_xor(s, d, 64);
  if (lane == 0) red[wv] = s;
  __syncthreads();
  const float mean = (red[0] + red[1] + red[2] + red[3]) * (1.f / 1024.f);
  const float dx = v.x - mean, dy = v.y - mean, dz = v.z - mean, dw = v.w - mean;
  float s2 = dx * dx + dy * dy + dz * dz + dw * dw;
#pragma unroll
  for (int d = 1; d < 64; d <<= 1) s2 += __shfl_xor(s2, d, 64);
  if (lane == 0) red[4 + wv] = s2;
  __syncthreads();
  const float var = (red[4] + red[5] + red[6] + red[7]) * (1.f / 1024.f);
  const float rs = rsqrtf(var + 1e-6f);
  const float4v g4 = ((const float4v*)gw)[t], b4 = ((const float4v*)bw)[t];
  s16x4 o;
  o[0] = f2bf(dx * rs * g4.x + b4.x);
  o[1] = f2bf(dy * rs * g4.y + b4.y);
  o[2] = f2bf(dz * rs * g4.z + b4.z);
  o[3] = f2bf(dw * rs * g4.w + b4.w);
  ((s16x4*)(out + (size_t)row * HIDN))[t] = o;
}

// ---------------------------------------------------------------- GEMM main loop (shared)
DEV void gemm_main(const short* __restrict__ A, const short* __restrict__ Bt, int K,
                   int m0, int n0, int tid, int wm, int wn, int lr, int lg,
                   short* As, short* Bs, f32x4 acc[4][4]) {
  for (int k0 = 0; k0 < K; k0 += 32) {
#pragma unroll
    for (int c = tid; c < 512; c += 256) {
      const int row = c >> 2, col = (c & 3) * 8;
      gl_lds16(A + (size_t)(m0 + row) * K + k0 + col, (char*)As + c * 16);
      gl_lds16(Bt + (size_t)(n0 + row) * K + k0 + col, (char*)Bs + c * 16);
    }
    __syncthreads();
    s16x8 af[4], bf[4];
#pragma unroll
    for (int fi = 0; fi < 4; ++fi) af[fi] = *(const s16x8*)&As[(wm + fi * 16 + lr) * 32 + lg * 8];
#pragma unroll
    for (int fj = 0; fj < 4; ++fj) bf[fj] = *(const s16x8*)&Bs[(wn + fj * 16 + lr) * 32 + lg * 8];
#pragma unroll
    for (int fi = 0; fi < 4; ++fi)
#pragma unroll
      for (int fj = 0; fj < 4; ++fj) acc[fi][fj] = MFMA16(af[fi], bf[fj], acc[fi][fj]);
    __syncthreads();
  }
}

// ---------------------------------------------------------------- generic GEMM epilogues
enum { OM_GELU = 0, OM_RESID = 1 };

template <int OM>
__global__ __launch_bounds__(256) void k_gemm(const short* __restrict__ A,
                                              const short* __restrict__ Bt,
                                              const float* __restrict__ bias,
                                              const float* __restrict__ resid,
                                              void* __restrict__ out,
                                              int M, int N, int K) {
  __shared__ short As[128 * 32];
  __shared__ short Bs[128 * 32];
  const int tid = threadIdx.x, lane = tid & 63, wave = tid >> 6;
  const int m0 = blockIdx.y * 128, n0 = blockIdx.x * 128;
  const int wm = (wave >> 1) * 64, wn = (wave & 1) * 64;
  const int lr = lane & 15, lg = lane >> 4;

  f32x4 acc[4][4];
#pragma unroll
  for (int i = 0; i < 4; ++i)
#pragma unroll
    for (int j = 0; j < 4; ++j) acc[i][j] = (f32x4){0.f, 0.f, 0.f, 0.f};
  gemm_main(A, Bt, K, m0, n0, tid, wm, wn, lr, lg, As, Bs, acc);

#pragma unroll
  for (int fi = 0; fi < 4; ++fi)
#pragma unroll
    for (int fj = 0; fj < 4; ++fj) {
      const int n = n0 + wn + fj * 16 + lr;
      const float bv = bias[n];
#pragma unroll
      for (int r = 0; r < 4; ++r) {
        const int m = m0 + wm + fi * 16 + lg * 4 + r;
        float v = acc[fi][fj][r] + bv;
        if constexpr (OM == OM_GELU) {
          const float z = 0.7978845608028654f * (v + 0.044715f * v * v * v);
          const float th = 1.f - 2.f / (1.f + __expf(2.f * z));
          ((short*)out)[(size_t)m * N + n] = f2bf(0.5f * v * (1.f + th));
        } else {  // OM_RESID, fp32 out
          ((float*)out)[(size_t)m * N + n] = v + resid[(size_t)m * N + n];
        }
      }
    }
}

// ---------------------------------------------------------------- fused QKV projection GEMM
__global__ __launch_bounds__(256) void k_gemm_qkv(const short* __restrict__ A,
                                                  const short* __restrict__ Bt,
                                                  const float* __restrict__ bq,
                                                  const float* __restrict__ bk,
                                                  const float* __restrict__ bv,
                                                  short* __restrict__ qo,
                                                  short* __restrict__ ko,
                                                  short* __restrict__ vo) {
  __shared__ short As[128 * 32];
  __shared__ short Bs[128 * 32];
  const int tid = threadIdx.x, lane = tid & 63, wave = tid >> 6;
  const int m0 = blockIdx.y * 128, n0 = blockIdx.x * 128;
  const int wm = (wave >> 1) * 64, wn = (wave & 1) * 64;
  const int lr = lane & 15, lg = lane >> 4;

  f32x4 acc[4][4];
#pragma unroll
  for (int i = 0; i < 4; ++i)
#pragma unroll
    for (int j = 0; j < 4; ++j) acc[i][j] = (f32x4){0.f, 0.f, 0.f, 0.f};
  gemm_main(A, Bt, 1024, m0, n0, tid, wm, wn, lr, lg, As, Bs, acc);

#pragma unroll
  for (int fi = 0; fi < 4; ++fi)
#pragma unroll
    for (int fj = 0; fj < 4; ++fj) {
      const int n = n0 + wn + fj * 16 + lr;
      const int proj = n >> 10, nn = n & 1023;
      const int hh = nn >> 6, dd = nn & 63;
      const float bvv = (proj == 0 ? bq : proj == 1 ? bk : bv)[nn];
#pragma unroll
      for (int r = 0; r < 4; ++r) {
        const int m = m0 + wm + fi * 16 + lg * 4 + r;
        const int b = m >> 11, s = m & (SS - 1);
        const float v = acc[fi][fj][r] + bvv;
        if (proj == 2)
          vo[(((size_t)b * NHH + hh) * DH + dd) * SS + s] = f2bf(v);
        else
          (proj == 0 ? qo : ko)[(((size_t)b * NHH + hh) * SS + s) * DH + dd] = f2bf(v);
      }
    }
}

// ---------------------------------------------------------------- fused pos projection GEMM
__global__ __launch_bounds__(256) void k_gemm_pos(const short* __restrict__ A,
                                                  const short* __restrict__ Bt,
                                                  const float* __restrict__ bpk,
                                                  const float* __restrict__ bpq,
                                                  short* __restrict__ pko,
                                                  short* __restrict__ pqo) {
  __shared__ short As[128 * 32];
  __shared__ short Bs[128 * 32];
  const int tid = threadIdx.x, lane = tid & 63, wave = tid >> 6;
  const int m0 = blockIdx.y * 128, n0 = blockIdx.x * 128;
  const int wm = (wave >> 1) * 64, wn = (wave & 1) * 64;
  const int lr = lane & 15, lg = lane >> 4;

  f32x4 acc[4][4];
#pragma unroll
  for (int i = 0; i < 4; ++i)
#pragma unroll
    for (int j = 0; j < 4; ++j) acc[i][j] = (f32x4){0.f, 0.f, 0.f, 0.f};
  gemm_main(A, Bt, 1024, m0, n0, tid, wm, wn, lr, lg, As, Bs, acc);

#pragma unroll
  for (int fi = 0; fi < 4; ++fi)
#pragma unroll
    for (int fj = 0; fj < 4; ++fj) {
      const int n = n0 + wn + fj * 16 + lr;
      const int pos = n >> 10, nn = n & 1023;
      const int hh = nn >> 6, dd = nn & 63;
      const float bvv = (pos == 0 ? bpk : bpq)[nn];
      short* ob = pos == 0 ? pko : pqo;
#pragma unroll
      for (int r = 0; r < 4; ++r) {
        const int m = m0 + wm + fi * 16 + lg * 4 + r;
        ob[((size_t)hh * TWOK + m) * DH + dd] = f2bf(acc[fi][fj][r] + bvv);
      }
    }
}

// ---------------------------------------------------------------- merged pos-attention GEMM
// z = [isP2c:1][b:1][hl:3]. Natural layouts: c2p[bhl][i][cc], p2c[bhl][j][cp];
// p2c epilogue extracts edge cols 0/1023 -> p2cE.
__global__ __launch_bounds__(256) void k_posgemm(const short* __restrict__ qh,
                                                 const short* __restrict__ kh,
                                                 const short* __restrict__ posk,
                                                 const short* __restrict__ posq,
                                                 short* __restrict__ c2pO,
                                                 short* __restrict__ p2cO,
                                                 short* __restrict__ p2cE, int h0) {
  __shared__ short As[128 * 64];
  __shared__ short Bs[128 * 64];
  const int tid = threadIdx.x, lane = tid & 63, wave = tid >> 6;
  const int z = blockIdx.z;
  const int hl = z & (HG - 1), b = (z >> 3) & 1, isP = z >> 4;
  const int h = h0 + hl;
  const int bhl = b * HG + hl;
  const int m0 = blockIdx.y * 128, n0 = blockIdx.x * 128;
  const int wm = (wave >> 1) * 64, wn = (wave & 1) * 64;
  const int lr = lane & 15, lg = lane >> 4;
  const short* Ab = (isP ? kh : qh) + ((size_t)b * NHH + h) * SS * DH;
  const short* Pb = (isP ? posq : posk) + (size_t)h * TWOK * DH;
  short* ob = (isP ? p2cO : c2pO) + (size_t)bhl * SS * TWOK;

#pragma unroll
  for (int c = tid; c < 1024; c += 256) {
    const int row = c >> 3, col = (c & 7) * 8;
    gl_lds16(Ab + (size_t)(m0 + row) * DH + col, (char*)As + c * 16);
    gl_lds16(Pb + (size_t)(n0 + row) * DH + col, (char*)Bs + c * 16);
  }
  __syncthreads();

  f32x4 acc[4][4];
#pragma unroll
  for (int i = 0; i < 4; ++i)
#pragma unroll
    for (int j = 0; j < 4; ++j) acc[i][j] = (f32x4){0.f, 0.f, 0.f, 0.f};

#pragma unroll
  for (int ks = 0; ks < 2; ++ks) {
    s16x8 af[4], bf[4];
#pragma unroll
    for (int fi = 0; fi < 4; ++fi) af[fi] = *(const s16x8*)&As[(wm + fi * 16 + lr) * 64 + ks * 32 + lg * 8];
#pragma unroll
    for (int fj = 0; fj < 4; ++fj) bf[fj] = *(const s16x8*)&Bs[(wn + fj * 16 + lr) * 64 + ks * 32 + lg * 8];
#pragma unroll
    for (int fi = 0; fi < 4; ++fi)
#pragma unroll
      for (int fj = 0; fj < 4; ++fj) acc[fi][fj] = MFMA16(af[fi], bf[fj], acc[fi][fj]);
  }

#pragma unroll
  for (int fi = 0; fi < 4; ++fi)
#pragma unroll
    for (int fj = 0; fj < 4; ++fj) {
      const int n = n0 + wn + fj * 16 + lr;
#pragma unroll
      for (int r = 0; r < 4; ++r) {
        const int m = m0 + wm + fi * 16 + lg * 4 + r;
        const short val = f2bf(acc[fi][fj][r]);
        ob[(size_t)m * TWOK + n] = val;
        if (isP) {
          if (n == 0)        p2cE[((size_t)bhl * 2 + 0) * SS + m] = val;
          if (n == TWOK - 1) p2cE[((size_t)bhl * 2 + 1) * SS + m] = val;
        }
      }
    }
}

// ---------------------------------------------------------------- flash disentangled attention
// R12 swapped-QK^T body + (a) K-fragment double-buffering (static A/B, K-only: R5/R7
// failed by buffering everything) and (b) bijective XCD swizzle (2048 = 8*256) so each
// (b,hl)'s 128 i-tile blocks share one XCD's L2 for K/V and near-band p2c.
__global__ __launch_bounds__(512) void k_attn(const short* __restrict__ qh,
                                              const short* __restrict__ kh,
                                              const short* __restrict__ vT,
                                              const short* __restrict__ c2p,
                                              const short* __restrict__ p2c,
                                              const short* __restrict__ p2cE,
                                              const int* __restrict__ mask,
                                              short* __restrict__ ao, int h0) {
  extern __shared__ char dynL[];
  char* c2pL = dynL + OFF_C2P;
  const int* maskL = (const int*)(dynL + OFF_MSK);
  float (*Om)[16][68] = (float(*)[16][68])(dynL + OFF_OVL);
  short (*Ps)[16][72] = (short(*)[16][72])(dynL + OFF_OVL);
  __shared__ float Mm[8][16];
  __shared__ float Lm[8][16];

  const int tid = threadIdx.x, lane = tid & 63, wv = tid >> 6;   // wv in [0,8)
  const int lr = lane & 15, lg = lane >> 4;

  const int orig = blockIdx.x;
  const int bid = (orig & 7) * 256 + (orig >> 3);   // XCD swizzle, bijective (2048=8*256)
  const int itile = bid & 127;
  const int hl = (bid >> 7) & (HG - 1);
  const int b = bid >> 10;
  const int h = h0 + hl;
  const int i0 = itile * 16;
  const size_t bhoff = ((size_t)b * NHH + h) * SS * DH;
  const size_t bhl = (size_t)b * HG + hl;
  const int jq0 = wv * (SS / 8);         // 256-wide j-strip per wave

  // ---- stage c2p rows (i0..i0+15) + mask into LDS
  for (int u = tid; u < 2048; u += 512) {
    const int ri = u >> 7, off = (u & 127) * 16;
    gl_lds16((const char*)(c2p + (bhl * SS + (size_t)(i0 + ri)) * TWOK) + off,
             c2pL + ri * ROWB + off);
  }
  gl_lds16((const char*)(mask + (size_t)b * SS) + tid * 16, (char*)(dynL + OFF_MSK) + tid * 16);

  // Q B-frag (col = row i0+lr)
  const short* qrow = qh + bhoff + (size_t)(i0 + lr) * DH + lg * 8;
  const s16x8 qa0 = *(const s16x8*)qrow;
  const s16x8 qa1 = *(const s16x8*)(qrow + 32);

  __syncthreads();   // staging complete

  // per-lane saturation constants for row i = i0+lr
  const float cLo = bfu(*(const unsigned short*)(c2pL + lr * ROWB));
  const float cHi = bfu(*(const unsigned short*)(c2pL + lr * ROWB + (TWOK - 1) * 2));
  const unsigned short* p2cb = (const unsigned short*)(p2c + bhl * SS * TWOK);
  const unsigned short* pE0 = (const unsigned short*)(p2cE + (bhl * 2 + 0) * SS);
  const unsigned short* pE1 = (const unsigned short*)(p2cE + (bhl * 2 + 1) * SS);

  f32x4 oacc[4];
  float mrow = -1e30f, lrow = 0.f;       // per-lane state for row i0+lr
#pragma unroll
  for (int r = 0; r < 4; ++r) oacc[r] = (f32x4){0.f, 0.f, 0.f, 0.f};

  const short* kbase = kh + bhoff;

  // ---- K fragment loader (8 loads, 32 VGPR per buffer)
  auto loadK = [&](int jt, s16x8 k0[4], s16x8 k1[4]) {
    const int j0 = jq0 + jt * 64;
#pragma unroll
    for (int fj = 0; fj < 4; ++fj) {
      const short* krow = kbase + (size_t)(j0 + fj * 16 + lr) * DH + lg * 8;
      k0[fj] = *(const s16x8*)krow;
      k1[fj] = *(const s16x8*)(krow + 32);
    }
  };

  // ---- full tile compute from prefetched K frags
  auto computeTile = [&](int jt, const s16x8 k0[4], const s16x8 k1[4]) {
    const int j0 = jq0 + jt * 64;
    const int d0 = i0 - j0;

    // c2c scores via SWAPPED MFMA: col=i=lr, row=j_local=lg*4+r
    f32x4 sacc[4];
#pragma unroll
    for (int fj = 0; fj < 4; ++fj) {
      f32x4 a = (f32x4){0.f, 0.f, 0.f, 0.f};
      a = MFMA16(k0[fj], qa0, a);
      a = MFMA16(k1[fj], qa1, a);
      sacc[fj] = a;
    }

    // position terms; lane's scores: (i = i0+lr, j = j0 + fj*16 + lg*4 + r)
    const int jbase = j0 + lg * 4;
    float pvv[4][4];
    if (d0 >= 576) {          // cc==1023, cp==0 -> cHi + pE0[j]
#pragma unroll
      for (int fj = 0; fj < 4; ++fj)
#pragma unroll
        for (int r = 0; r < 4; ++r) {
          const int jb = jbase + fj * 16 + r;
          const bool ok = maskL[jb] != 0;
          const float s = (sacc[fj][r] + cHi + bfu(pE0[jb])) * ATT_SCALE;
          pvv[fj][r] = ok ? s : -1e9f;
        }
    } else if (d0 <= -528) {  // cc==0, cp==1023 -> cLo + pE1[j]
#pragma unroll
      for (int fj = 0; fj < 4; ++fj)
#pragma unroll
        for (int r = 0; r < 4; ++r) {
          const int jb = jbase + fj * 16 + r;
          const bool ok = maskL[jb] != 0;
          const float s = (sacc[fj][r] + cLo + bfu(pE1[jb])) * ATT_SCALE;
          pvv[fj][r] = ok ? s : -1e9f;
        }
    } else {                  // near band: c2p from LDS (own row), p2c from global (contig)
      const int ii = i0 + lr;
#pragma unroll
      for (int fj = 0; fj < 4; ++fj)
#pragma unroll
        for (int r = 0; r < 4; ++r) {
          const int jb = jbase + fj * 16 + r;
          const bool ok = maskL[jb] != 0;
          const int dl = ii - jb;
          const int cc = imin(imax(dl + 512, 0), 1023);
          const int cp = imin(imax(512 - dl, 0), 1023);
          const float c2pv = bfu(*(const unsigned short*)(c2pL + lr * ROWB + cc * 2));
          const float p2cv = bfu(p2cb[(size_t)jb * TWOK + cp]);
          const float s = (sacc[fj][r] + c2pv + p2cv) * ATT_SCALE;
          pvv[fj][r] = ok ? s : -1e9f;
        }
    }

    // online softmax: in-register reduce over 16 + 2 shfl across lg quad
    float mx = pvv[0][0];
#pragma unroll
    for (int fj = 0; fj < 4; ++fj)
#pragma unroll
      for (int r = 0; r < 4; ++r) mx = fmaxf(mx, pvv[fj][r]);
    mx = fmaxf(mx, __shfl_xor(mx, 16, 64));
    mx = fmaxf(mx, __shfl_xor(mx, 32, 64));
    const float mnew = fmaxf(mrow, mx);
    const float corr = __expf(mrow - mnew);
    float sm = 0.f;
#pragma unroll
    for (int fj = 0; fj < 4; ++fj)
#pragma unroll
      for (int r = 0; r < 4; ++r) { pvv[fj][r] = __expf(pvv[fj][r] - mnew); sm += pvv[fj][r]; }
    sm += __shfl_xor(sm, 16, 64);
    sm += __shfl_xor(sm, 32, 64);
    lrow = lrow * corr + sm;
    mrow = mnew;

    // route corr to oacc rows (row il = lg*4+r held at lane il)
    float corr4[4];
#pragma unroll
    for (int r = 0; r < 4; ++r) corr4[r] = __shfl(corr, lg * 4 + r, 64);
#pragma unroll
    for (int fd = 0; fd < 4; ++fd)
#pragma unroll
      for (int r = 0; r < 4; ++r) oacc[fd][r] *= corr4[r];

    // P -> Ps (row i=lr, vector s16x4 per fj; wave-private, no barrier)
#pragma unroll
    for (int fj = 0; fj < 4; ++fj) {
      s16x4 pw;
#pragma unroll
      for (int r = 0; r < 4; ++r) pw[r] = f2bf(pvv[fj][r]);
      *(s16x4*)&Ps[wv][lr][fj * 16 + lg * 4] = pw;
    }

    // PV (A-frag from Ps, V frags from L1/L2)
    const s16x8 pa0 = *(const s16x8*)&Ps[wv][lr][lg * 8];
    const s16x8 pa1 = *(const s16x8*)&Ps[wv][lr][32 + lg * 8];
#pragma unroll
    for (int fd = 0; fd < 4; ++fd) {
      const short* vrow = vT + bhoff + (size_t)(fd * 16 + lr) * SS + j0 + lg * 8;
      const s16x8 v0 = *(const s16x8*)vrow;
      const s16x8 v1 = *(const s16x8*)(vrow + 32);
      oacc[fd] = MFMA16(pa0, v0, oacc[fd]);
      oacc[fd] = MFMA16(pa1, v1, oacc[fd]);
    }
  };

  // ---- 4 tiles, K double-buffered (static A/B; prefetch issues before tile compute)
  s16x8 kA0[4], kA1[4], kB0[4], kB1[4];
  loadK(0, kA0, kA1);
  loadK(1, kB0, kB1);
  computeTile(0, kA0, kA1);
  loadK(2, kA0, kA1);
  computeTile(1, kB0, kB1);
  loadK(3, kB0, kB1);
  computeTile(2, kA0, kA1);
  computeTile(3, kB0, kB1);

  // ---- split-KV merge across the 8 waves (Om overlays Ps: barrier first)
  __syncthreads();
#pragma unroll
  for (int fd = 0; fd < 4; ++fd)
#pragma unroll
    for (int r = 0; r < 4; ++r)
      Om[wv][lg * 4 + r][fd * 16 + lr] = oacc[fd][r];
  if (lg == 0) { Mm[wv][lr] = mrow; Lm[wv][lr] = lrow; }
  __syncthreads();

  // waves 0-3 finalize (each one 16-col slice), summing over all 8 partials
  if (wv < 4) {
#pragma unroll
    for (int r = 0; r < 4; ++r) {
      const int il = lg * 4 + r;
      float mt = -1e30f;
#pragma unroll
      for (int w = 0; w < 8; ++w) mt = fmaxf(mt, Mm[w][il]);
      float L = 0.f, o = 0.f;
#pragma unroll
      for (int w = 0; w < 8; ++w) {
        const float sc = __expf(Mm[w][il] - mt);
        L += Lm[w][il] * sc;
        o += Om[w][il][wv * 16 + lr] * sc;
      }
      ao[((size_t)b * SS + i0 + il) * HIDN + h * DH + wv * 16 + lr] = f2bf(o / L);
    }
  }
}

// ---------------------------------------------------------------- launch
extern "C" void kernel_launch(void* const* d_in, const int* in_sizes, int n_in,
                              void* d_out, int out_size, void* d_ws, size_t ws_size,
                              hipStream_t stream) {
  const float* x   = (const float*)d_in[0];
  const int* mask  = (const int*)d_in[1];
  const float* Wq  = (const float*)d_in[2];  const float* bq  = (const float*)d_in[3];
  const float* Wk  = (const float*)d_in[4];  const float* bk  = (const float*)d_in[5];
  const float* Wv  = (const float*)d_in[6];  const float* bv  = (const float*)d_in[7];
  const float* Wo  = (const float*)d_in[8];  const float* bo  = (const float*)d_in[9];
  const float* rel = (const float*)d_in[10];
  const float* Wpk = (const float*)d_in[11]; const float* bpk = (const float*)d_in[12];
  const float* Wpq = (const float*)d_in[13]; const float* bpq = (const float*)d_in[14];
  const float* g1  = (const float*)d_in[15]; const float* be1 = (const float*)d_in[16];
  const float* g2  = (const float*)d_in[17]; const float* be2 = (const float*)d_in[18];
  const float* W1  = (const float*)d_in[19]; const float* bf1 = (const float*)d_in[20];
  const float* W2  = (const float*)d_in[21]; const float* bf2 = (const float*)d_in[22];
  float* out = (float*)d_out;

  char* ws = (char*)d_ws;
  const size_t MB = (size_t)1 << 20;
  // persistent
  short* aoB   = (short*)(ws + 0 * MB);    // 8 MB
  short* qhB   = (short*)(ws + 8 * MB);    // 8 MB
  short* khB   = (short*)(ws + 16 * MB);   // 8 MB
  short* vTB   = (short*)(ws + 24 * MB);   // 8 MB
  short* poskB = (short*)(ws + 32 * MB);   // 2 MB
  short* posqB = (short*)(ws + 34 * MB);   // 2 MB
  // stage 1-3 transient
  short* xn    = (short*)(ws + 36 * MB);   // 8 MB
  short* WqT   = (short*)(ws + 44 * MB);   // 2 MB  } contiguous 6 MB = fused QKV Bt
  short* WkT   = (short*)(ws + 46 * MB);   // 2 MB  }
  short* WvT   = (short*)(ws + 48 * MB);   // 2 MB  }
  short* WpkT  = (short*)(ws + 50 * MB);   // 2 MB  } contiguous 4 MB = fused pos Bt
  short* WpqT  = (short*)(ws + 52 * MB);   // 2 MB  }
  short* relbf = (short*)(ws + 54 * MB);   // 2 MB
  // stage 4 (HG=8)
  short* c2pG  = (short*)(ws + 36 * MB);   // 64 MB  [B, HG, S(i), 2K(cc)]
  short* p2cG  = (short*)(ws + 100 * MB);  // 64 MB  [B, HG, S(j), 2K(cp)]
  short* p2cE  = (short*)(ws + 164 * MB);  // 128 KB edge columns
  // stage 5
  short* WoT   = (short*)(ws + 36 * MB);   // 2 MB
  short* hnB   = (short*)(ws + 38 * MB);   // 8 MB
  short* W1T   = (short*)(ws + 46 * MB);   // 8 MB
  short* W2T   = (short*)(ws + 54 * MB);   // 8 MB
  short* midB  = (short*)(ws + 62 * MB);   // 32 MB
  (void)ws_size; (void)in_sizes; (void)n_in; (void)out_size;

  const int M = BB * SS;  // 4096

  // ---- stage 1: batched weight prep + LN
  TCBatch tc;
  tc.in[0] = Wq;  tc.out[0] = WqT;
  tc.in[1] = Wk;  tc.out[1] = WkT;
  tc.in[2] = Wv;  tc.out[2] = WvT;
  tc.in[3] = Wpk; tc.out[3] = WpkT;
  tc.in[4] = Wpq; tc.out[4] = WpqT;
  k_tcast5<<<dim3(32, 32, 5), 256, 0, stream>>>(tc);
  k_cast<<<1024, 256, 0, stream>>>(rel, relbf, 1024 * 1024 / 4);
  k_ln<<<M, 256, 0, stream>>>(x, g1, be1, xn);

  // ---- stage 2: fused projections
  k_gemm_qkv<<<dim3(24, 32), 256, 0, stream>>>(xn, WqT, bq, bk, bv, qhB, khB, vTB);
  k_gemm_pos<<<dim3(16, 8), 256, 0, stream>>>(relbf, WpkT, bpk, bpq, poskB, posqB);

  // ---- stage 4: attention in 2 head-groups of 8
  for (int g = 0; g < NHH / HG; ++g) {
    const int h0 = g * HG;
    k_posgemm<<<dim3(8, 16, 4 * HG), 256, 0, stream>>>(qhB, khB, poskB, posqB,
                                                       c2pG, p2cG, p2cE, h0);
    k_attn<<<BB * HG * 128, 512, DYN_LDS, stream>>>(qhB, khB, vTB, c2pG, p2cG, p2cE,
                                                    mask, aoB, h0);
  }

  // ---- stage 5
  k_tcast<<<dim3(32, 32), 256, 0, stream>>>(Wo, WoT, 1024, 1024);
  k_gemm<OM_RESID><<<dim3(8, 32), 256, 0, stream>>>(aoB, WoT, bo, x, out, M, 1024, 1024);
  k_ln<<<M, 256, 0, stream>>>(out, g2, be2, hnB);
  k_tcast<<<dim3(128, 32), 256, 0, stream>>>(W1, W1T, 1024, 4096);
  k_tcast<<<dim3(32, 128), 256, 0, stream>>>(W2, W2T, 4096, 1024);
  k_gemm<OM_GELU><<<dim3(32, 32), 256, 0, stream>>>(hnB, W1T, bf1, nullptr, midB, M, 4096, 1024);
  k_gemm<OM_RESID><<<dim3(8, 32), 256, 0, stream>>>(midB, W2T, bf2, out, out, M, 1024, 4096);
}

// Round 14
// 614.552 us; speedup vs baseline: 1.1014x; 1.1014x over previous
//
#include <hip/hip_runtime.h>
#include <cstdint>
#include <cstddef>

#define DEV __device__ __forceinline__

typedef __attribute__((ext_vector_type(4))) float  f32x4;
typedef __attribute__((ext_vector_type(4))) float  float4v;
typedef __attribute__((ext_vector_type(8))) short  s16x8;
typedef __attribute__((ext_vector_type(4))) short  s16x4;

static constexpr int BB = 2, SS = 2048, HIDN = 1024, NHH = 16, FFN = 4096, DH = 64;
static constexpr int TWOK = 1024;                  // 2*K
static constexpr int HG = 8;                       // heads per attention group
static constexpr float ATT_SCALE = 0.07216878364870322f;  // 1/sqrt(3*DH)

// k_attn dynamic LDS: c2p rows (16 x 2056B) + mask + overlay
static constexpr int ROWB = 2056;
static constexpr int OFF_C2P = 0;                  // 32896
static constexpr int OFF_MSK = 32896;              // 8192
static constexpr int OFF_OVL = 41088;              // 34816 (Om overlay / Ps)
static constexpr int DYN_LDS = 75904;              // ~76KB -> 2 blocks/CU

DEV short f2bf(float f) {
  union { float f; uint32_t u; } v; v.f = f;
  uint32_t r = (v.u + 0x7fffu + ((v.u >> 16) & 1u)) >> 16;
  return (short)r;
}
DEV float bfu(unsigned short u) {
  union { uint32_t u; float f; } v; v.u = ((uint32_t)u) << 16; return v.f;
}
DEV int imin(int a, int b) { return a < b ? a : b; }
DEV int imax(int a, int b) { return a > b ? a : b; }

DEV void gl_lds16(const void* g, void* l) {
  __builtin_amdgcn_global_load_lds((const __attribute__((address_space(1))) void*)g,
                                   (__attribute__((address_space(3))) void*)l, 16, 0, 0);
}

#define MFMA16(a, b, c) __builtin_amdgcn_mfma_f32_16x16x32_bf16((a), (b), (c), 0, 0, 0)

// ---------------------------------------------------------------- transpose+cast (generic)
__global__ __launch_bounds__(256) void k_tcast(const float* __restrict__ in,
                                               short* __restrict__ out, int R, int C) {
  __shared__ float t[32][33];
  const int bx = blockIdx.x * 32, by = blockIdx.y * 32;
  const int tx = threadIdx.x & 31, ty = threadIdx.x >> 5;
#pragma unroll
  for (int r = ty; r < 32; r += 8) t[r][tx] = in[(size_t)(by + r) * C + bx + tx];
  __syncthreads();
#pragma unroll
  for (int c = ty; c < 32; c += 8) out[(size_t)(bx + c) * R + by + tx] = f2bf(t[tx][c]);
}

// ---------------------------------------------------------------- batched 1024x1024 transpose+cast
struct TCBatch { const float* in[5]; short* out[5]; };
__global__ __launch_bounds__(256) void k_tcast5(TCBatch tc) {
  __shared__ float t[32][33];
  const float* in = tc.in[blockIdx.z];
  short* out = tc.out[blockIdx.z];
  const int bx = blockIdx.x * 32, by = blockIdx.y * 32;
  const int tx = threadIdx.x & 31, ty = threadIdx.x >> 5;
#pragma unroll
  for (int r = ty; r < 32; r += 8) t[r][tx] = in[(size_t)(by + r) * 1024 + bx + tx];
  __syncthreads();
#pragma unroll
  for (int c = ty; c < 32; c += 8) out[(size_t)(bx + c) * 1024 + by + tx] = f2bf(t[tx][c]);
}

// ---------------------------------------------------------------- plain cast
__global__ __launch_bounds__(256) void k_cast(const float* __restrict__ in,
                                              short* __restrict__ out, int n4) {
  const int i = blockIdx.x * 256 + threadIdx.x;
  if (i < n4) {
    float4v v = ((const float4v*)in)[i];
    s16x4 o; o[0] = f2bf(v.x); o[1] = f2bf(v.y); o[2] = f2bf(v.z); o[3] = f2bf(v.w);
    ((s16x4*)out)[i] = o;
  }
}

// ---------------------------------------------------------------- layernorm
__global__ __launch_bounds__(256) void k_ln(const float* __restrict__ x,
                                            const float* __restrict__ gw,
                                            const float* __restrict__ bw,
                                            short* __restrict__ out) {
  const int row = blockIdx.x, t = threadIdx.x, lane = t & 63, wv = t >> 6;
  __shared__ float red[8];
  const float4v v = ((const float4v*)(x + (size_t)row * HIDN))[t];
  float s = v.x + v.y + v.z + v.w;
#pragma unroll
  for (int d = 1; d < 64; d <<= 1) s += __shfl_xor(s, d, 64);
  if (lane == 0) red[wv] = s;
  __syncthreads();
  const float mean = (red[0] + red[1] + red[2] + red[3]) * (1.f / 1024.f);
  const float dx = v.x - mean, dy = v.y - mean, dz = v.z - mean, dw = v.w - mean;
  float s2 = dx * dx + dy * dy + dz * dz + dw * dw;
#pragma unroll
  for (int d = 1; d < 64; d <<= 1) s2 += __shfl_xor(s2, d, 64);
  if (lane == 0) red[4 + wv] = s2;
  __syncthreads();
  const float var = (red[4] + red[5] + red[6] + red[7]) * (1.f / 1024.f);
  const float rs = rsqrtf(var + 1e-6f);
  const float4v g4 = ((const float4v*)gw)[t], b4 = ((const float4v*)bw)[t];
  s16x4 o;
  o[0] = f2bf(dx * rs * g4.x + b4.x);
  o[1] = f2bf(dy * rs * g4.y + b4.y);
  o[2] = f2bf(dz * rs * g4.z + b4.z);
  o[3] = f2bf(dw * rs * g4.w + b4.w);
  ((s16x4*)(out + (size_t)row * HIDN))[t] = o;
}

// ---------------------------------------------------------------- GEMM main loop (shared)
DEV void gemm_main(const short* __restrict__ A, const short* __restrict__ Bt, int K,
                   int m0, int n0, int tid, int wm, int wn, int lr, int lg,
                   short* As, short* Bs, f32x4 acc[4][4]) {
  for (int k0 = 0; k0 < K; k0 += 32) {
#pragma unroll
    for (int c = tid; c < 512; c += 256) {
      const int row = c >> 2, col = (c & 3) * 8;
      gl_lds16(A + (size_t)(m0 + row) * K + k0 + col, (char*)As + c * 16);
      gl_lds16(Bt + (size_t)(n0 + row) * K + k0 + col, (char*)Bs + c * 16);
    }
    __syncthreads();
    s16x8 af[4], bf[4];
#pragma unroll
    for (int fi = 0; fi < 4; ++fi) af[fi] = *(const s16x8*)&As[(wm + fi * 16 + lr) * 32 + lg * 8];
#pragma unroll
    for (int fj = 0; fj < 4; ++fj) bf[fj] = *(const s16x8*)&Bs[(wn + fj * 16 + lr) * 32 + lg * 8];
#pragma unroll
    for (int fi = 0; fi < 4; ++fi)
#pragma unroll
      for (int fj = 0; fj < 4; ++fj) acc[fi][fj] = MFMA16(af[fi], bf[fj], acc[fi][fj]);
    __syncthreads();
  }
}

// ---------------------------------------------------------------- generic GEMM epilogues
enum { OM_GELU = 0, OM_RESID = 1 };

template <int OM>
__global__ __launch_bounds__(256) void k_gemm(const short* __restrict__ A,
                                              const short* __restrict__ Bt,
                                              const float* __restrict__ bias,
                                              const float* __restrict__ resid,
                                              void* __restrict__ out,
                                              int M, int N, int K) {
  __shared__ short As[128 * 32];
  __shared__ short Bs[128 * 32];
  const int tid = threadIdx.x, lane = tid & 63, wave = tid >> 6;
  const int m0 = blockIdx.y * 128, n0 = blockIdx.x * 128;
  const int wm = (wave >> 1) * 64, wn = (wave & 1) * 64;
  const int lr = lane & 15, lg = lane >> 4;

  f32x4 acc[4][4];
#pragma unroll
  for (int i = 0; i < 4; ++i)
#pragma unroll
    for (int j = 0; j < 4; ++j) acc[i][j] = (f32x4){0.f, 0.f, 0.f, 0.f};
  gemm_main(A, Bt, K, m0, n0, tid, wm, wn, lr, lg, As, Bs, acc);

#pragma unroll
  for (int fi = 0; fi < 4; ++fi)
#pragma unroll
    for (int fj = 0; fj < 4; ++fj) {
      const int n = n0 + wn + fj * 16 + lr;
      const float bv = bias[n];
#pragma unroll
      for (int r = 0; r < 4; ++r) {
        const int m = m0 + wm + fi * 16 + lg * 4 + r;
        float v = acc[fi][fj][r] + bv;
        if constexpr (OM == OM_GELU) {
          const float z = 0.7978845608028654f * (v + 0.044715f * v * v * v);
          const float th = 1.f - 2.f / (1.f + __expf(2.f * z));
          ((short*)out)[(size_t)m * N + n] = f2bf(0.5f * v * (1.f + th));
        } else {  // OM_RESID, fp32 out
          ((float*)out)[(size_t)m * N + n] = v + resid[(size_t)m * N + n];
        }
      }
    }
}

// ---------------------------------------------------------------- fused QKV projection GEMM
__global__ __launch_bounds__(256) void k_gemm_qkv(const short* __restrict__ A,
                                                  const short* __restrict__ Bt,
                                                  const float* __restrict__ bq,
                                                  const float* __restrict__ bk,
                                                  const float* __restrict__ bv,
                                                  short* __restrict__ qo,
                                                  short* __restrict__ ko,
                                                  short* __restrict__ vo) {
  __shared__ short As[128 * 32];
  __shared__ short Bs[128 * 32];
  const int tid = threadIdx.x, lane = tid & 63, wave = tid >> 6;
  const int m0 = blockIdx.y * 128, n0 = blockIdx.x * 128;
  const int wm = (wave >> 1) * 64, wn = (wave & 1) * 64;
  const int lr = lane & 15, lg = lane >> 4;

  f32x4 acc[4][4];
#pragma unroll
  for (int i = 0; i < 4; ++i)
#pragma unroll
    for (int j = 0; j < 4; ++j) acc[i][j] = (f32x4){0.f, 0.f, 0.f, 0.f};
  gemm_main(A, Bt, 1024, m0, n0, tid, wm, wn, lr, lg, As, Bs, acc);

#pragma unroll
  for (int fi = 0; fi < 4; ++fi)
#pragma unroll
    for (int fj = 0; fj < 4; ++fj) {
      const int n = n0 + wn + fj * 16 + lr;
      const int proj = n >> 10, nn = n & 1023;
      const int hh = nn >> 6, dd = nn & 63;
      const float bvv = (proj == 0 ? bq : proj == 1 ? bk : bv)[nn];
#pragma unroll
      for (int r = 0; r < 4; ++r) {
        const int m = m0 + wm + fi * 16 + lg * 4 + r;
        const int b = m >> 11, s = m & (SS - 1);
        const float v = acc[fi][fj][r] + bvv;
        if (proj == 2)
          vo[(((size_t)b * NHH + hh) * DH + dd) * SS + s] = f2bf(v);
        else
          (proj == 0 ? qo : ko)[(((size_t)b * NHH + hh) * SS + s) * DH + dd] = f2bf(v);
      }
    }
}

// ---------------------------------------------------------------- fused pos projection GEMM
__global__ __launch_bounds__(256) void k_gemm_pos(const short* __restrict__ A,
                                                  const short* __restrict__ Bt,
                                                  const float* __restrict__ bpk,
                                                  const float* __restrict__ bpq,
                                                  short* __restrict__ pko,
                                                  short* __restrict__ pqo) {
  __shared__ short As[128 * 32];
  __shared__ short Bs[128 * 32];
  const int tid = threadIdx.x, lane = tid & 63, wave = tid >> 6;
  const int m0 = blockIdx.y * 128, n0 = blockIdx.x * 128;
  const int wm = (wave >> 1) * 64, wn = (wave & 1) * 64;
  const int lr = lane & 15, lg = lane >> 4;

  f32x4 acc[4][4];
#pragma unroll
  for (int i = 0; i < 4; ++i)
#pragma unroll
    for (int j = 0; j < 4; ++j) acc[i][j] = (f32x4){0.f, 0.f, 0.f, 0.f};
  gemm_main(A, Bt, 1024, m0, n0, tid, wm, wn, lr, lg, As, Bs, acc);

#pragma unroll
  for (int fi = 0; fi < 4; ++fi)
#pragma unroll
    for (int fj = 0; fj < 4; ++fj) {
      const int n = n0 + wn + fj * 16 + lr;
      const int pos = n >> 10, nn = n & 1023;
      const int hh = nn >> 6, dd = nn & 63;
      const float bvv = (pos == 0 ? bpk : bpq)[nn];
      short* ob = pos == 0 ? pko : pqo;
#pragma unroll
      for (int r = 0; r < 4; ++r) {
        const int m = m0 + wm + fi * 16 + lg * 4 + r;
        ob[((size_t)hh * TWOK + m) * DH + dd] = f2bf(acc[fi][fj][r] + bvv);
      }
    }
}

// ---------------------------------------------------------------- merged pos-attention GEMM
// z = [isP2c:1][b:1][hl:3]. Natural layouts: c2p[bhl][i][cc], p2c[bhl][j][cp];
// p2c epilogue extracts edge cols 0/1023 -> p2cE.
__global__ __launch_bounds__(256) void k_posgemm(const short* __restrict__ qh,
                                                 const short* __restrict__ kh,
                                                 const short* __restrict__ posk,
                                                 const short* __restrict__ posq,
                                                 short* __restrict__ c2pO,
                                                 short* __restrict__ p2cO,
                                                 short* __restrict__ p2cE, int h0) {
  __shared__ short As[128 * 64];
  __shared__ short Bs[128 * 64];
  const int tid = threadIdx.x, lane = tid & 63, wave = tid >> 6;
  const int z = blockIdx.z;
  const int hl = z & (HG - 1), b = (z >> 3) & 1, isP = z >> 4;
  const int h = h0 + hl;
  const int bhl = b * HG + hl;
  const int m0 = blockIdx.y * 128, n0 = blockIdx.x * 128;
  const int wm = (wave >> 1) * 64, wn = (wave & 1) * 64;
  const int lr = lane & 15, lg = lane >> 4;
  const short* Ab = (isP ? kh : qh) + ((size_t)b * NHH + h) * SS * DH;
  const short* Pb = (isP ? posq : posk) + (size_t)h * TWOK * DH;
  short* ob = (isP ? p2cO : c2pO) + (size_t)bhl * SS * TWOK;

#pragma unroll
  for (int c = tid; c < 1024; c += 256) {
    const int row = c >> 3, col = (c & 7) * 8;
    gl_lds16(Ab + (size_t)(m0 + row) * DH + col, (char*)As + c * 16);
    gl_lds16(Pb + (size_t)(n0 + row) * DH + col, (char*)Bs + c * 16);
  }
  __syncthreads();

  f32x4 acc[4][4];
#pragma unroll
  for (int i = 0; i < 4; ++i)
#pragma unroll
    for (int j = 0; j < 4; ++j) acc[i][j] = (f32x4){0.f, 0.f, 0.f, 0.f};

#pragma unroll
  for (int ks = 0; ks < 2; ++ks) {
    s16x8 af[4], bf[4];
#pragma unroll
    for (int fi = 0; fi < 4; ++fi) af[fi] = *(const s16x8*)&As[(wm + fi * 16 + lr) * 64 + ks * 32 + lg * 8];
#pragma unroll
    for (int fj = 0; fj < 4; ++fj) bf[fj] = *(const s16x8*)&Bs[(wn + fj * 16 + lr) * 64 + ks * 32 + lg * 8];
#pragma unroll
    for (int fi = 0; fi < 4; ++fi)
#pragma unroll
      for (int fj = 0; fj < 4; ++fj) acc[fi][fj] = MFMA16(af[fi], bf[fj], acc[fi][fj]);
  }

#pragma unroll
  for (int fi = 0; fi < 4; ++fi)
#pragma unroll
    for (int fj = 0; fj < 4; ++fj) {
      const int n = n0 + wn + fj * 16 + lr;
#pragma unroll
      for (int r = 0; r < 4; ++r) {
        const int m = m0 + wm + fi * 16 + lg * 4 + r;
        const short val = f2bf(acc[fi][fj][r]);
        ob[(size_t)m * TWOK + n] = val;
        if (isP) {
          if (n == 0)        p2cE[((size_t)bhl * 2 + 0) * SS + m] = val;
          if (n == TWOK - 1) p2cE[((size_t)bhl * 2 + 1) * SS + m] = val;
        }
      }
    }
}

// ---------------------------------------------------------------- flash disentangled attention
// R12 swapped-QK^T body (best measured: 146.7 us, occ 41%) + T13 defer-max (skip rescale
// when wave-uniformly max growth <= 8) + T5 setprio around MFMA clusters. No swizzle,
// no K-dbuf (R13 lesson: both serialize the chain / the XCD L2 port).
__global__ __launch_bounds__(512) void k_attn(const short* __restrict__ qh,
                                              const short* __restrict__ kh,
                                              const short* __restrict__ vT,
                                              const short* __restrict__ c2p,
                                              const short* __restrict__ p2c,
                                              const short* __restrict__ p2cE,
                                              const int* __restrict__ mask,
                                              short* __restrict__ ao, int h0) {
  extern __shared__ char dynL[];
  char* c2pL = dynL + OFF_C2P;
  const int* maskL = (const int*)(dynL + OFF_MSK);
  float (*Om)[16][68] = (float(*)[16][68])(dynL + OFF_OVL);
  short (*Ps)[16][72] = (short(*)[16][72])(dynL + OFF_OVL);
  __shared__ float Mm[8][16];
  __shared__ float Lm[8][16];

  const int tid = threadIdx.x, lane = tid & 63, wv = tid >> 6;   // wv in [0,8)
  const int lr = lane & 15, lg = lane >> 4;

  const int bid = blockIdx.x;            // 2048 = b:1 | hl:3 | itile:7
  const int itile = bid & 127;
  const int hl = (bid >> 7) & (HG - 1);
  const int b = bid >> 10;
  const int h = h0 + hl;
  const int i0 = itile * 16;
  const size_t bhoff = ((size_t)b * NHH + h) * SS * DH;
  const size_t bhl = (size_t)b * HG + hl;
  const int jq0 = wv * (SS / 8);         // 256-wide j-strip per wave

  // ---- stage c2p rows (i0..i0+15) + mask into LDS
  for (int u = tid; u < 2048; u += 512) {
    const int ri = u >> 7, off = (u & 127) * 16;
    gl_lds16((const char*)(c2p + (bhl * SS + (size_t)(i0 + ri)) * TWOK) + off,
             c2pL + ri * ROWB + off);
  }
  gl_lds16((const char*)(mask + (size_t)b * SS) + tid * 16, (char*)(dynL + OFF_MSK) + tid * 16);

  // Q B-frag (col = row i0+lr)
  const short* qrow = qh + bhoff + (size_t)(i0 + lr) * DH + lg * 8;
  const s16x8 qa0 = *(const s16x8*)qrow;
  const s16x8 qa1 = *(const s16x8*)(qrow + 32);

  __syncthreads();   // staging complete

  // per-lane saturation constants for row i = i0+lr
  const float cLo = bfu(*(const unsigned short*)(c2pL + lr * ROWB));
  const float cHi = bfu(*(const unsigned short*)(c2pL + lr * ROWB + (TWOK - 1) * 2));
  const unsigned short* p2cb = (const unsigned short*)(p2c + bhl * SS * TWOK);
  const unsigned short* pE0 = (const unsigned short*)(p2cE + (bhl * 2 + 0) * SS);
  const unsigned short* pE1 = (const unsigned short*)(p2cE + (bhl * 2 + 1) * SS);

  f32x4 oacc[4];
  float mrow = -1e30f, lrow = 0.f;       // per-lane state for row i0+lr
#pragma unroll
  for (int r = 0; r < 4; ++r) oacc[r] = (f32x4){0.f, 0.f, 0.f, 0.f};

  for (int jt = 0; jt < SS / 8 / 64; ++jt) {   // 4 tiles per wave
    const int j0 = jq0 + jt * 64;
    const int d0 = i0 - j0;

    // ---- c2c scores via SWAPPED MFMA: C[j_local][i] with col=i=lr, row=j=lg*4+r
    f32x4 sacc[4];
    __builtin_amdgcn_s_setprio(1);
#pragma unroll
    for (int fj = 0; fj < 4; ++fj) {
      const short* krow = kh + bhoff + (size_t)(j0 + fj * 16 + lr) * DH + lg * 8;
      const s16x8 k0 = *(const s16x8*)krow;
      const s16x8 k1 = *(const s16x8*)(krow + 32);
      f32x4 a = (f32x4){0.f, 0.f, 0.f, 0.f};
      a = MFMA16(k0, qa0, a);            // SWAPPED: K as A, Q as B
      a = MFMA16(k1, qa1, a);
      sacc[fj] = a;
    }
    __builtin_amdgcn_s_setprio(0);

    // ---- position terms; lane's scores: (i = i0+lr, j = j0 + fj*16 + lg*4 + r)
    const int jbase = j0 + lg * 4;
    float pvv[4][4];
    if (d0 >= 576) {          // cc==1023, cp==0 -> cHi + pE0[j]
#pragma unroll
      for (int fj = 0; fj < 4; ++fj)
#pragma unroll
        for (int r = 0; r < 4; ++r) {
          const int jb = jbase + fj * 16 + r;
          const bool ok = maskL[jb] != 0;
          const float s = (sacc[fj][r] + cHi + bfu(pE0[jb])) * ATT_SCALE;
          pvv[fj][r] = ok ? s : -1e9f;
        }
    } else if (d0 <= -528) {  // cc==0, cp==1023 -> cLo + pE1[j]
#pragma unroll
      for (int fj = 0; fj < 4; ++fj)
#pragma unroll
        for (int r = 0; r < 4; ++r) {
          const int jb = jbase + fj * 16 + r;
          const bool ok = maskL[jb] != 0;
          const float s = (sacc[fj][r] + cLo + bfu(pE1[jb])) * ATT_SCALE;
          pvv[fj][r] = ok ? s : -1e9f;
        }
    } else {                  // near band: c2p from LDS (own row), p2c from global (contig)
      const int ii = i0 + lr;
#pragma unroll
      for (int fj = 0; fj < 4; ++fj)
#pragma unroll
        for (int r = 0; r < 4; ++r) {
          const int jb = jbase + fj * 16 + r;
          const bool ok = maskL[jb] != 0;
          const int dl = ii - jb;
          const int cc = imin(imax(dl + 512, 0), 1023);
          const int cp = imin(imax(512 - dl, 0), 1023);
          const float c2pv = bfu(*(const unsigned short*)(c2pL + lr * ROWB + cc * 2));
          const float p2cv = bfu(p2cb[(size_t)jb * TWOK + cp]);
          const float s = (sacc[fj][r] + c2pv + p2cv) * ATT_SCALE;
          pvv[fj][r] = ok ? s : -1e9f;
        }
    }

    // ---- online softmax: in-register reduce + 2 shfl; T13 defer-max (wave-uniform)
    float mx = pvv[0][0];
#pragma unroll
    for (int fj = 0; fj < 4; ++fj)
#pragma unroll
      for (int r = 0; r < 4; ++r) mx = fmaxf(mx, pvv[fj][r]);
    mx = fmaxf(mx, __shfl_xor(mx, 16, 64));
    mx = fmaxf(mx, __shfl_xor(mx, 32, 64));

    const bool defer = __all(mx <= mrow + 8.f);
    if (defer) {
      // keep mrow; P bounded by e^8 ~ 2981 (bf16/f32-safe); no rescale needed
      float sm = 0.f;
#pragma unroll
      for (int fj = 0; fj < 4; ++fj)
#pragma unroll
        for (int r = 0; r < 4; ++r) { pvv[fj][r] = __expf(pvv[fj][r] - mrow); sm += pvv[fj][r]; }
      sm += __shfl_xor(sm, 16, 64);
      sm += __shfl_xor(sm, 32, 64);
      lrow += sm;
    } else {
      const float mnew = fmaxf(mrow, mx);
      const float corr = __expf(mrow - mnew);
      float sm = 0.f;
#pragma unroll
      for (int fj = 0; fj < 4; ++fj)
#pragma unroll
        for (int r = 0; r < 4; ++r) { pvv[fj][r] = __expf(pvv[fj][r] - mnew); sm += pvv[fj][r]; }
      sm += __shfl_xor(sm, 16, 64);
      sm += __shfl_xor(sm, 32, 64);
      lrow = lrow * corr + sm;
      mrow = mnew;
      // route corr to oacc rows (row il = lg*4+r held at lane il)
      float corr4[4];
#pragma unroll
      for (int r = 0; r < 4; ++r) corr4[r] = __shfl(corr, lg * 4 + r, 64);
#pragma unroll
      for (int fd = 0; fd < 4; ++fd)
#pragma unroll
        for (int r = 0; r < 4; ++r) oacc[fd][r] *= corr4[r];
    }

    // ---- P -> Ps (row i=lr, vector s16x4 per fj; wave-private, no barrier)
#pragma unroll
    for (int fj = 0; fj < 4; ++fj) {
      s16x4 pw;
#pragma unroll
      for (int r = 0; r < 4; ++r) pw[r] = f2bf(pvv[fj][r]);
      *(s16x4*)&Ps[wv][lr][fj * 16 + lg * 4] = pw;
    }

    // ---- PV (A-frag from Ps, V frags from L1/L2)
    const s16x8 pa0 = *(const s16x8*)&Ps[wv][lr][lg * 8];
    const s16x8 pa1 = *(const s16x8*)&Ps[wv][lr][32 + lg * 8];
    __builtin_amdgcn_s_setprio(1);
#pragma unroll
    for (int fd = 0; fd < 4; ++fd) {
      const short* vrow = vT + bhoff + (size_t)(fd * 16 + lr) * SS + j0 + lg * 8;
      const s16x8 v0 = *(const s16x8*)vrow;
      const s16x8 v1 = *(const s16x8*)(vrow + 32);
      oacc[fd] = MFMA16(pa0, v0, oacc[fd]);
      oacc[fd] = MFMA16(pa1, v1, oacc[fd]);
    }
    __builtin_amdgcn_s_setprio(0);
  }

  // ---- split-KV merge across the 8 waves (Om overlays Ps: barrier first)
  __syncthreads();
#pragma unroll
  for (int fd = 0; fd < 4; ++fd)
#pragma unroll
    for (int r = 0; r < 4; ++r)
      Om[wv][lg * 4 + r][fd * 16 + lr] = oacc[fd][r];
  if (lg == 0) { Mm[wv][lr] = mrow; Lm[wv][lr] = lrow; }
  __syncthreads();

  // waves 0-3 finalize (each one 16-col slice), summing over all 8 partials
  if (wv < 4) {
#pragma unroll
    for (int r = 0; r < 4; ++r) {
      const int il = lg * 4 + r;
      float mt = -1e30f;
#pragma unroll
      for (int w = 0; w < 8; ++w) mt = fmaxf(mt, Mm[w][il]);
      float L = 0.f, o = 0.f;
#pragma unroll
      for (int w = 0; w < 8; ++w) {
        const float sc = __expf(Mm[w][il] - mt);
        L += Lm[w][il] * sc;
        o += Om[w][il][wv * 16 + lr] * sc;
      }
      ao[((size_t)b * SS + i0 + il) * HIDN + h * DH + wv * 16 + lr] = f2bf(o / L);
    }
  }
}

// ---------------------------------------------------------------- launch
extern "C" void kernel_launch(void* const* d_in, const int* in_sizes, int n_in,
                              void* d_out, int out_size, void* d_ws, size_t ws_size,
                              hipStream_t stream) {
  const float* x   = (const float*)d_in[0];
  const int* mask  = (const int*)d_in[1];
  const float* Wq  = (const float*)d_in[2];  const float* bq  = (const float*)d_in[3];
  const float* Wk  = (const float*)d_in[4];  const float* bk  = (const float*)d_in[5];
  const float* Wv  = (const float*)d_in[6];  const float* bv  = (const float*)d_in[7];
  const float* Wo  = (const float*)d_in[8];  const float* bo  = (const float*)d_in[9];
  const float* rel = (const float*)d_in[10];
  const float* Wpk = (const float*)d_in[11]; const float* bpk = (const float*)d_in[12];
  const float* Wpq = (const float*)d_in[13]; const float* bpq = (const float*)d_in[14];
  const float* g1  = (const float*)d_in[15]; const float* be1 = (const float*)d_in[16];
  const float* g2  = (const float*)d_in[17]; const float* be2 = (const float*)d_in[18];
  const float* W1  = (const float*)d_in[19]; const float* bf1 = (const float*)d_in[20];
  const float* W2  = (const float*)d_in[21]; const float* bf2 = (const float*)d_in[22];
  float* out = (float*)d_out;

  char* ws = (char*)d_ws;
  const size_t MB = (size_t)1 << 20;
  // persistent
  short* aoB   = (short*)(ws + 0 * MB);    // 8 MB
  short* qhB   = (short*)(ws + 8 * MB);    // 8 MB
  short* khB   = (short*)(ws + 16 * MB);   // 8 MB
  short* vTB   = (short*)(ws + 24 * MB);   // 8 MB
  short* poskB = (short*)(ws + 32 * MB);   // 2 MB
  short* posqB = (short*)(ws + 34 * MB);   // 2 MB
  // stage 1-3 transient
  short* xn    = (short*)(ws + 36 * MB);   // 8 MB
  short* WqT   = (short*)(ws + 44 * MB);   // 2 MB  } contiguous 6 MB = fused QKV Bt
  short* WkT   = (short*)(ws + 46 * MB);   // 2 MB  }
  short* WvT   = (short*)(ws + 48 * MB);   // 2 MB  }
  short* WpkT  = (short*)(ws + 50 * MB);   // 2 MB  } contiguous 4 MB = fused pos Bt
  short* WpqT  = (short*)(ws + 52 * MB);   // 2 MB  }
  short* relbf = (short*)(ws + 54 * MB);   // 2 MB
  // stage 4 (HG=8)
  short* c2pG  = (short*)(ws + 36 * MB);   // 64 MB  [B, HG, S(i), 2K(cc)]
  short* p2cG  = (short*)(ws + 100 * MB);  // 64 MB  [B, HG, S(j), 2K(cp)]
  short* p2cE  = (short*)(ws + 164 * MB);  // 128 KB edge columns
  // stage 5
  short* WoT   = (short*)(ws + 36 * MB);   // 2 MB
  short* hnB   = (short*)(ws + 38 * MB);   // 8 MB
  short* W1T   = (short*)(ws + 46 * MB);   // 8 MB
  short* W2T   = (short*)(ws + 54 * MB);   // 8 MB
  short* midB  = (short*)(ws + 62 * MB);   // 32 MB
  (void)ws_size; (void)in_sizes; (void)n_in; (void)out_size;

  const int M = BB * SS;  // 4096

  // ---- stage 1: batched weight prep + LN
  TCBatch tc;
  tc.in[0] = Wq;  tc.out[0] = WqT;
  tc.in[1] = Wk;  tc.out[1] = WkT;
  tc.in[2] = Wv;  tc.out[2] = WvT;
  tc.in[3] = Wpk; tc.out[3] = WpkT;
  tc.in[4] = Wpq; tc.out[4] = WpqT;
  k_tcast5<<<dim3(32, 32, 5), 256, 0, stream>>>(tc);
  k_cast<<<1024, 256, 0, stream>>>(rel, relbf, 1024 * 1024 / 4);
  k_ln<<<M, 256, 0, stream>>>(x, g1, be1, xn);

  // ---- stage 2: fused projections
  k_gemm_qkv<<<dim3(24, 32), 256, 0, stream>>>(xn, WqT, bq, bk, bv, qhB, khB, vTB);
  k_gemm_pos<<<dim3(16, 8), 256, 0, stream>>>(relbf, WpkT, bpk, bpq, poskB, posqB);

  // ---- stage 4: attention in 2 head-groups of 8
  for (int g = 0; g < NHH / HG; ++g) {
    const int h0 = g * HG;
    k_posgemm<<<dim3(8, 16, 4 * HG), 256, 0, stream>>>(qhB, khB, poskB, posqB,
                                                       c2pG, p2cG, p2cE, h0);
    k_attn<<<BB * HG * 128, 512, DYN_LDS, stream>>>(qhB, khB, vTB, c2pG, p2cG, p2cE,
                                                    mask, aoB, h0);
  }

  // ---- stage 5
  k_tcast<<<dim3(32, 32), 256, 0, stream>>>(Wo, WoT, 1024, 1024);
  k_gemm<OM_RESID><<<dim3(8, 32), 256, 0, stream>>>(aoB, WoT, bo, x, out, M, 1024, 1024);
  k_ln<<<M, 256, 0, stream>>>(out, g2, be2, hnB);
  k_tcast<<<dim3(128, 32), 256, 0, stream>>>(W1, W1T, 1024, 4096);
  k_tcast<<<dim3(32, 128), 256, 0, stream>>>(W2, W2T, 4096, 1024);
  k_gemm<OM_GELU><<<dim3(32, 32), 256, 0, stream>>>(hnB, W1T, bf1, nullptr, midB, M, 4096, 1024);
  k_gemm<OM_RESID><<<dim3(8, 32), 256, 0, stream>>>(midB, W2T, bf2, out, out, M, 1024, 4096);
}

// Round 15
// 603.990 us; speedup vs baseline: 1.1206x; 1.0175x over previous
//
#include <hip/hip_runtime.h>
#include <cstdint>
#include <cstddef>

#define DEV __device__ __forceinline__

typedef __attribute__((ext_vector_type(4))) float  f32x4;
typedef __attribute__((ext_vector_type(4))) float  float4v;
typedef __attribute__((ext_vector_type(8))) short  s16x8;
typedef __attribute__((ext_vector_type(4))) short  s16x4;

static constexpr int BB = 2, SS = 2048, HIDN = 1024, NHH = 16, FFN = 4096, DH = 64;
static constexpr int TWOK = 1024;                  // 2*K
static constexpr int HG = 8;                       // heads per attention group
static constexpr float ATT_SCALE = 0.07216878364870322f;  // 1/sqrt(3*DH)

// k_attn dynamic LDS: c2p rows (16 x 2056B) + mask + overlay
static constexpr int ROWB = 2056;
static constexpr int OFF_C2P = 0;                  // 32896
static constexpr int OFF_MSK = 32896;              // 8192
static constexpr int OFF_OVL = 41088;              // 34816 (Om overlay / Ps)
static constexpr int DYN_LDS = 75904;              // ~76KB -> 2 blocks/CU

DEV short f2bf(float f) {
  union { float f; uint32_t u; } v; v.f = f;
  uint32_t r = (v.u + 0x7fffu + ((v.u >> 16) & 1u)) >> 16;
  return (short)r;
}
DEV float bfu(unsigned short u) {
  union { uint32_t u; float f; } v; v.u = ((uint32_t)u) << 16; return v.f;
}
DEV int imin(int a, int b) { return a < b ? a : b; }
DEV int imax(int a, int b) { return a > b ? a : b; }

DEV void gl_lds16(const void* g, void* l) {
  __builtin_amdgcn_global_load_lds((const __attribute__((address_space(1))) void*)g,
                                   (__attribute__((address_space(3))) void*)l, 16, 0, 0);
}

#define MFMA16(a, b, c) __builtin_amdgcn_mfma_f32_16x16x32_bf16((a), (b), (c), 0, 0, 0)

// ---------------------------------------------------------------- transpose+cast (generic)
__global__ __launch_bounds__(256) void k_tcast(const float* __restrict__ in,
                                               short* __restrict__ out, int R, int C) {
  __shared__ float t[32][33];
  const int bx = blockIdx.x * 32, by = blockIdx.y * 32;
  const int tx = threadIdx.x & 31, ty = threadIdx.x >> 5;
#pragma unroll
  for (int r = ty; r < 32; r += 8) t[r][tx] = in[(size_t)(by + r) * C + bx + tx];
  __syncthreads();
#pragma unroll
  for (int c = ty; c < 32; c += 8) out[(size_t)(bx + c) * R + by + tx] = f2bf(t[tx][c]);
}

// ---------------------------------------------------------------- batched 1024x1024 transpose+cast
struct TCBatch { const float* in[5]; short* out[5]; };
__global__ __launch_bounds__(256) void k_tcast5(TCBatch tc) {
  __shared__ float t[32][33];
  const float* in = tc.in[blockIdx.z];
  short* out = tc.out[blockIdx.z];
  const int bx = blockIdx.x * 32, by = blockIdx.y * 32;
  const int tx = threadIdx.x & 31, ty = threadIdx.x >> 5;
#pragma unroll
  for (int r = ty; r < 32; r += 8) t[r][tx] = in[(size_t)(by + r) * 1024 + bx + tx];
  __syncthreads();
#pragma unroll
  for (int c = ty; c < 32; c += 8) out[(size_t)(bx + c) * 1024 + by + tx] = f2bf(t[tx][c]);
}

// ---------------------------------------------------------------- plain cast
__global__ __launch_bounds__(256) void k_cast(const float* __restrict__ in,
                                              short* __restrict__ out, int n4) {
  const int i = blockIdx.x * 256 + threadIdx.x;
  if (i < n4) {
    float4v v = ((const float4v*)in)[i];
    s16x4 o; o[0] = f2bf(v.x); o[1] = f2bf(v.y); o[2] = f2bf(v.z); o[3] = f2bf(v.w);
    ((s16x4*)out)[i] = o;
  }
}

// ---------------------------------------------------------------- layernorm
__global__ __launch_bounds__(256) void k_ln(const float* __restrict__ x,
                                            const float* __restrict__ gw,
                                            const float* __restrict__ bw,
                                            short* __restrict__ out) {
  const int row = blockIdx.x, t = threadIdx.x, lane = t & 63, wv = t >> 6;
  __shared__ float red[8];
  const float4v v = ((const float4v*)(x + (size_t)row * HIDN))[t];
  float s = v.x + v.y + v.z + v.w;
#pragma unroll
  for (int d = 1; d < 64; d <<= 1) s += __shfl_xor(s, d, 64);
  if (lane == 0) red[wv] = s;
  __syncthreads();
  const float mean = (red[0] + red[1] + red[2] + red[3]) * (1.f / 1024.f);
  const float dx = v.x - mean, dy = v.y - mean, dz = v.z - mean, dw = v.w - mean;
  float s2 = dx * dx + dy * dy + dz * dz + dw * dw;
#pragma unroll
  for (int d = 1; d < 64; d <<= 1) s2 += __shfl_xor(s2, d, 64);
  if (lane == 0) red[4 + wv] = s2;
  __syncthreads();
  const float var = (red[4] + red[5] + red[6] + red[7]) * (1.f / 1024.f);
  const float rs = rsqrtf(var + 1e-6f);
  const float4v g4 = ((const float4v*)gw)[t], b4 = ((const float4v*)bw)[t];
  s16x4 o;
  o[0] = f2bf(dx * rs * g4.x + b4.x);
  o[1] = f2bf(dy * rs * g4.y + b4.y);
  o[2] = f2bf(dz * rs * g4.z + b4.z);
  o[3] = f2bf(dw * rs * g4.w + b4.w);
  ((s16x4*)(out + (size_t)row * HIDN))[t] = o;
}

// ---------------------------------------------------------------- GEMM main loop (shared)
DEV void gemm_main(const short* __restrict__ A, const short* __restrict__ Bt, int K,
                   int m0, int n0, int tid, int wm, int wn, int lr, int lg,
                   short* As, short* Bs, f32x4 acc[4][4]) {
  for (int k0 = 0; k0 < K; k0 += 32) {
#pragma unroll
    for (int c = tid; c < 512; c += 256) {
      const int row = c >> 2, col = (c & 3) * 8;
      gl_lds16(A + (size_t)(m0 + row) * K + k0 + col, (char*)As + c * 16);
      gl_lds16(Bt + (size_t)(n0 + row) * K + k0 + col, (char*)Bs + c * 16);
    }
    __syncthreads();
    s16x8 af[4], bf[4];
#pragma unroll
    for (int fi = 0; fi < 4; ++fi) af[fi] = *(const s16x8*)&As[(wm + fi * 16 + lr) * 32 + lg * 8];
#pragma unroll
    for (int fj = 0; fj < 4; ++fj) bf[fj] = *(const s16x8*)&Bs[(wn + fj * 16 + lr) * 32 + lg * 8];
#pragma unroll
    for (int fi = 0; fi < 4; ++fi)
#pragma unroll
      for (int fj = 0; fj < 4; ++fj) acc[fi][fj] = MFMA16(af[fi], bf[fj], acc[fi][fj]);
    __syncthreads();
  }
}

// ---------------------------------------------------------------- generic GEMM epilogues
enum { OM_GELU = 0, OM_RESID = 1 };

template <int OM>
__global__ __launch_bounds__(256) void k_gemm(const short* __restrict__ A,
                                              const short* __restrict__ Bt,
                                              const float* __restrict__ bias,
                                              const float* __restrict__ resid,
                                              void* __restrict__ out,
                                              int M, int N, int K) {
  __shared__ short As[128 * 32];
  __shared__ short Bs[128 * 32];
  const int tid = threadIdx.x, lane = tid & 63, wave = tid >> 6;
  const int m0 = blockIdx.y * 128, n0 = blockIdx.x * 128;
  const int wm = (wave >> 1) * 64, wn = (wave & 1) * 64;
  const int lr = lane & 15, lg = lane >> 4;

  f32x4 acc[4][4];
#pragma unroll
  for (int i = 0; i < 4; ++i)
#pragma unroll
    for (int j = 0; j < 4; ++j) acc[i][j] = (f32x4){0.f, 0.f, 0.f, 0.f};
  gemm_main(A, Bt, K, m0, n0, tid, wm, wn, lr, lg, As, Bs, acc);

#pragma unroll
  for (int fi = 0; fi < 4; ++fi)
#pragma unroll
    for (int fj = 0; fj < 4; ++fj) {
      const int n = n0 + wn + fj * 16 + lr;
      const float bv = bias[n];
#pragma unroll
      for (int r = 0; r < 4; ++r) {
        const int m = m0 + wm + fi * 16 + lg * 4 + r;
        float v = acc[fi][fj][r] + bv;
        if constexpr (OM == OM_GELU) {
          const float z = 0.7978845608028654f * (v + 0.044715f * v * v * v);
          const float th = 1.f - 2.f / (1.f + __expf(2.f * z));
          ((short*)out)[(size_t)m * N + n] = f2bf(0.5f * v * (1.f + th));
        } else {  // OM_RESID, fp32 out
          ((float*)out)[(size_t)m * N + n] = v + resid[(size_t)m * N + n];
        }
      }
    }
}

// ---------------------------------------------------------------- fused QKV projection GEMM
// Q is pre-scaled by ATT_SCALE (Q feeds only c2c and c2p, both scaled score terms).
__global__ __launch_bounds__(256) void k_gemm_qkv(const short* __restrict__ A,
                                                  const short* __restrict__ Bt,
                                                  const float* __restrict__ bq,
                                                  const float* __restrict__ bk,
                                                  const float* __restrict__ bv,
                                                  short* __restrict__ qo,
                                                  short* __restrict__ ko,
                                                  short* __restrict__ vo) {
  __shared__ short As[128 * 32];
  __shared__ short Bs[128 * 32];
  const int tid = threadIdx.x, lane = tid & 63, wave = tid >> 6;
  const int m0 = blockIdx.y * 128, n0 = blockIdx.x * 128;
  const int wm = (wave >> 1) * 64, wn = (wave & 1) * 64;
  const int lr = lane & 15, lg = lane >> 4;

  f32x4 acc[4][4];
#pragma unroll
  for (int i = 0; i < 4; ++i)
#pragma unroll
    for (int j = 0; j < 4; ++j) acc[i][j] = (f32x4){0.f, 0.f, 0.f, 0.f};
  gemm_main(A, Bt, 1024, m0, n0, tid, wm, wn, lr, lg, As, Bs, acc);

#pragma unroll
  for (int fi = 0; fi < 4; ++fi)
#pragma unroll
    for (int fj = 0; fj < 4; ++fj) {
      const int n = n0 + wn + fj * 16 + lr;
      const int proj = n >> 10, nn = n & 1023;
      const int hh = nn >> 6, dd = nn & 63;
      const float bvv = (proj == 0 ? bq : proj == 1 ? bk : bv)[nn];
#pragma unroll
      for (int r = 0; r < 4; ++r) {
        const int m = m0 + wm + fi * 16 + lg * 4 + r;
        const int b = m >> 11, s = m & (SS - 1);
        float v = acc[fi][fj][r] + bvv;
        if (proj == 0) v *= ATT_SCALE;   // pre-scale Q
        if (proj == 2)
          vo[(((size_t)b * NHH + hh) * DH + dd) * SS + s] = f2bf(v);
        else
          (proj == 0 ? qo : ko)[(((size_t)b * NHH + hh) * SS + s) * DH + dd] = f2bf(v);
      }
    }
}

// ---------------------------------------------------------------- fused pos projection GEMM
// pos_q is pre-scaled by ATT_SCALE (feeds only the p2c score term, incl. pE extracts).
__global__ __launch_bounds__(256) void k_gemm_pos(const short* __restrict__ A,
                                                  const short* __restrict__ Bt,
                                                  const float* __restrict__ bpk,
                                                  const float* __restrict__ bpq,
                                                  short* __restrict__ pko,
                                                  short* __restrict__ pqo) {
  __shared__ short As[128 * 32];
  __shared__ short Bs[128 * 32];
  const int tid = threadIdx.x, lane = tid & 63, wave = tid >> 6;
  const int m0 = blockIdx.y * 128, n0 = blockIdx.x * 128;
  const int wm = (wave >> 1) * 64, wn = (wave & 1) * 64;
  const int lr = lane & 15, lg = lane >> 4;

  f32x4 acc[4][4];
#pragma unroll
  for (int i = 0; i < 4; ++i)
#pragma unroll
    for (int j = 0; j < 4; ++j) acc[i][j] = (f32x4){0.f, 0.f, 0.f, 0.f};
  gemm_main(A, Bt, 1024, m0, n0, tid, wm, wn, lr, lg, As, Bs, acc);

#pragma unroll
  for (int fi = 0; fi < 4; ++fi)
#pragma unroll
    for (int fj = 0; fj < 4; ++fj) {
      const int n = n0 + wn + fj * 16 + lr;
      const int pos = n >> 10, nn = n & 1023;
      const int hh = nn >> 6, dd = nn & 63;
      const float bvv = (pos == 0 ? bpk : bpq)[nn];
      short* ob = pos == 0 ? pko : pqo;
      const float sc = pos == 0 ? 1.f : ATT_SCALE;
#pragma unroll
      for (int r = 0; r < 4; ++r) {
        const int m = m0 + wm + fi * 16 + lg * 4 + r;
        ob[((size_t)hh * TWOK + m) * DH + dd] = f2bf((acc[fi][fj][r] + bvv) * sc);
      }
    }
}

// ---------------------------------------------------------------- merged pos-attention GEMM
// z = [isP2c:1][b:1][hl:3]. Natural layouts: c2p[bhl][i][cc], p2c[bhl][j][cp];
// p2c epilogue extracts edge cols 0/1023 -> p2cE. (c2p rows arrive pre-scaled via Q;
// p2c rows pre-scaled via pos_q.)
__global__ __launch_bounds__(256) void k_posgemm(const short* __restrict__ qh,
                                                 const short* __restrict__ kh,
                                                 const short* __restrict__ posk,
                                                 const short* __restrict__ posq,
                                                 short* __restrict__ c2pO,
                                                 short* __restrict__ p2cO,
                                                 short* __restrict__ p2cE, int h0) {
  __shared__ short As[128 * 64];
  __shared__ short Bs[128 * 64];
  const int tid = threadIdx.x, lane = tid & 63, wave = tid >> 6;
  const int z = blockIdx.z;
  const int hl = z & (HG - 1), b = (z >> 3) & 1, isP = z >> 4;
  const int h = h0 + hl;
  const int bhl = b * HG + hl;
  const int m0 = blockIdx.y * 128, n0 = blockIdx.x * 128;
  const int wm = (wave >> 1) * 64, wn = (wave & 1) * 64;
  const int lr = lane & 15, lg = lane >> 4;
  const short* Ab = (isP ? kh : qh) + ((size_t)b * NHH + h) * SS * DH;
  const short* Pb = (isP ? posq : posk) + (size_t)h * TWOK * DH;
  short* ob = (isP ? p2cO : c2pO) + (size_t)bhl * SS * TWOK;

#pragma unroll
  for (int c = tid; c < 1024; c += 256) {
    const int row = c >> 3, col = (c & 7) * 8;
    gl_lds16(Ab + (size_t)(m0 + row) * DH + col, (char*)As + c * 16);
    gl_lds16(Pb + (size_t)(n0 + row) * DH + col, (char*)Bs + c * 16);
  }
  __syncthreads();

  f32x4 acc[4][4];
#pragma unroll
  for (int i = 0; i < 4; ++i)
#pragma unroll
    for (int j = 0; j < 4; ++j) acc[i][j] = (f32x4){0.f, 0.f, 0.f, 0.f};

#pragma unroll
  for (int ks = 0; ks < 2; ++ks) {
    s16x8 af[4], bf[4];
#pragma unroll
    for (int fi = 0; fi < 4; ++fi) af[fi] = *(const s16x8*)&As[(wm + fi * 16 + lr) * 64 + ks * 32 + lg * 8];
#pragma unroll
    for (int fj = 0; fj < 4; ++fj) bf[fj] = *(const s16x8*)&Bs[(wn + fj * 16 + lr) * 64 + ks * 32 + lg * 8];
#pragma unroll
    for (int fi = 0; fi < 4; ++fi)
#pragma unroll
      for (int fj = 0; fj < 4; ++fj) acc[fi][fj] = MFMA16(af[fi], bf[fj], acc[fi][fj]);
  }

#pragma unroll
  for (int fi = 0; fi < 4; ++fi)
#pragma unroll
    for (int fj = 0; fj < 4; ++fj) {
      const int n = n0 + wn + fj * 16 + lr;
#pragma unroll
      for (int r = 0; r < 4; ++r) {
        const int m = m0 + wm + fi * 16 + lg * 4 + r;
        const short val = f2bf(acc[fi][fj][r]);
        ob[(size_t)m * TWOK + n] = val;
        if (isP) {
          if (n == 0)        p2cE[((size_t)bhl * 2 + 0) * SS + m] = val;
          if (n == TWOK - 1) p2cE[((size_t)bhl * 2 + 1) * SS + m] = val;
        }
      }
    }
}

// ---------------------------------------------------------------- flash disentangled attention
// R12 body (best measured: 146.7 us, occ 41%): swapped QK^T (lane-local softmax), c2p
// from LDS, p2c contiguous from global, 512 thr / 8 j-strips, 2 blocks/CU.
// Scores arrive PRE-SCALED (Q and pos_q carry ATT_SCALE) -> no per-score multiply.
__global__ __launch_bounds__(512) void k_attn(const short* __restrict__ qh,
                                              const short* __restrict__ kh,
                                              const short* __restrict__ vT,
                                              const short* __restrict__ c2p,
                                              const short* __restrict__ p2c,
                                              const short* __restrict__ p2cE,
                                              const int* __restrict__ mask,
                                              short* __restrict__ ao, int h0) {
  extern __shared__ char dynL[];
  char* c2pL = dynL + OFF_C2P;
  const int* maskL = (const int*)(dynL + OFF_MSK);
  float (*Om)[16][68] = (float(*)[16][68])(dynL + OFF_OVL);
  short (*Ps)[16][72] = (short(*)[16][72])(dynL + OFF_OVL);
  __shared__ float Mm[8][16];
  __shared__ float Lm[8][16];

  const int tid = threadIdx.x, lane = tid & 63, wv = tid >> 6;   // wv in [0,8)
  const int lr = lane & 15, lg = lane >> 4;

  const int bid = blockIdx.x;            // 2048 = b:1 | hl:3 | itile:7
  const int itile = bid & 127;
  const int hl = (bid >> 7) & (HG - 1);
  const int b = bid >> 10;
  const int h = h0 + hl;
  const int i0 = itile * 16;
  const size_t bhoff = ((size_t)b * NHH + h) * SS * DH;
  const size_t bhl = (size_t)b * HG + hl;
  const int jq0 = wv * (SS / 8);         // 256-wide j-strip per wave

  // ---- stage c2p rows (i0..i0+15) + mask into LDS
  for (int u = tid; u < 2048; u += 512) {
    const int ri = u >> 7, off = (u & 127) * 16;
    gl_lds16((const char*)(c2p + (bhl * SS + (size_t)(i0 + ri)) * TWOK) + off,
             c2pL + ri * ROWB + off);
  }
  gl_lds16((const char*)(mask + (size_t)b * SS) + tid * 16, (char*)(dynL + OFF_MSK) + tid * 16);

  // Q B-frag (col = row i0+lr)
  const short* qrow = qh + bhoff + (size_t)(i0 + lr) * DH + lg * 8;
  const s16x8 qa0 = *(const s16x8*)qrow;
  const s16x8 qa1 = *(const s16x8*)(qrow + 32);

  __syncthreads();   // staging complete

  // per-lane saturation constants for row i = i0+lr
  const float cLo = bfu(*(const unsigned short*)(c2pL + lr * ROWB));
  const float cHi = bfu(*(const unsigned short*)(c2pL + lr * ROWB + (TWOK - 1) * 2));
  const unsigned short* p2cb = (const unsigned short*)(p2c + bhl * SS * TWOK);
  const unsigned short* pE0 = (const unsigned short*)(p2cE + (bhl * 2 + 0) * SS);
  const unsigned short* pE1 = (const unsigned short*)(p2cE + (bhl * 2 + 1) * SS);

  f32x4 oacc[4];
  float mrow = -1e30f, lrow = 0.f;       // per-lane state for row i0+lr
#pragma unroll
  for (int r = 0; r < 4; ++r) oacc[r] = (f32x4){0.f, 0.f, 0.f, 0.f};

  for (int jt = 0; jt < SS / 8 / 64; ++jt) {   // 4 tiles per wave
    const int j0 = jq0 + jt * 64;
    const int d0 = i0 - j0;

    // ---- c2c scores via SWAPPED MFMA: C[j_local][i] with col=i=lr, row=j=lg*4+r
    f32x4 sacc[4];
#pragma unroll
    for (int fj = 0; fj < 4; ++fj) {
      const short* krow = kh + bhoff + (size_t)(j0 + fj * 16 + lr) * DH + lg * 8;
      const s16x8 k0 = *(const s16x8*)krow;
      const s16x8 k1 = *(const s16x8*)(krow + 32);
      f32x4 a = (f32x4){0.f, 0.f, 0.f, 0.f};
      a = MFMA16(k0, qa0, a);            // SWAPPED: K as A, Q as B
      a = MFMA16(k1, qa1, a);
      sacc[fj] = a;
    }

    // ---- position terms; lane's scores: (i = i0+lr, j = j0 + fj*16 + lg*4 + r)
    const int jbase = j0 + lg * 4;
    float pvv[4][4];
    if (d0 >= 576) {          // cc==1023, cp==0 -> cHi + pE0[j]
#pragma unroll
      for (int fj = 0; fj < 4; ++fj)
#pragma unroll
        for (int r = 0; r < 4; ++r) {
          const int jb = jbase + fj * 16 + r;
          const bool ok = maskL[jb] != 0;
          const float s = sacc[fj][r] + cHi + bfu(pE0[jb]);
          pvv[fj][r] = ok ? s : -1e9f;
        }
    } else if (d0 <= -528) {  // cc==0, cp==1023 -> cLo + pE1[j]
#pragma unroll
      for (int fj = 0; fj < 4; ++fj)
#pragma unroll
        for (int r = 0; r < 4; ++r) {
          const int jb = jbase + fj * 16 + r;
          const bool ok = maskL[jb] != 0;
          const float s = sacc[fj][r] + cLo + bfu(pE1[jb]);
          pvv[fj][r] = ok ? s : -1e9f;
        }
    } else {                  // near band: c2p from LDS (own row), p2c from global (contig)
      const int ii = i0 + lr;
#pragma unroll
      for (int fj = 0; fj < 4; ++fj)
#pragma unroll
        for (int r = 0; r < 4; ++r) {
          const int jb = jbase + fj * 16 + r;
          const bool ok = maskL[jb] != 0;
          const int dl = ii - jb;
          const int cc = imin(imax(dl + 512, 0), 1023);
          const int cp = imin(imax(512 - dl, 0), 1023);
          const float c2pv = bfu(*(const unsigned short*)(c2pL + lr * ROWB + cc * 2));
          const float p2cv = bfu(p2cb[(size_t)jb * TWOK + cp]);
          const float s = sacc[fj][r] + c2pv + p2cv;
          pvv[fj][r] = ok ? s : -1e9f;
        }
    }

    // ---- online softmax: in-register reduce over 16 + 2 shfl across lg quad
    float mx = pvv[0][0];
#pragma unroll
    for (int fj = 0; fj < 4; ++fj)
#pragma unroll
      for (int r = 0; r < 4; ++r) mx = fmaxf(mx, pvv[fj][r]);
    mx = fmaxf(mx, __shfl_xor(mx, 16, 64));
    mx = fmaxf(mx, __shfl_xor(mx, 32, 64));
    const float mnew = fmaxf(mrow, mx);
    const float corr = __expf(mrow - mnew);
    float sm = 0.f;
#pragma unroll
    for (int fj = 0; fj < 4; ++fj)
#pragma unroll
      for (int r = 0; r < 4; ++r) { pvv[fj][r] = __expf(pvv[fj][r] - mnew); sm += pvv[fj][r]; }
    sm += __shfl_xor(sm, 16, 64);
    sm += __shfl_xor(sm, 32, 64);
    lrow = lrow * corr + sm;
    mrow = mnew;

    // route corr to oacc rows (row il = lg*4+r held at lane il)
    float corr4[4];
#pragma unroll
    for (int r = 0; r < 4; ++r) corr4[r] = __shfl(corr, lg * 4 + r, 64);
#pragma unroll
    for (int fd = 0; fd < 4; ++fd)
#pragma unroll
      for (int r = 0; r < 4; ++r) oacc[fd][r] *= corr4[r];

    // ---- P -> Ps (row i=lr, vector s16x4 per fj; wave-private, no barrier)
#pragma unroll
    for (int fj = 0; fj < 4; ++fj) {
      s16x4 pw;
#pragma unroll
      for (int r = 0; r < 4; ++r) pw[r] = f2bf(pvv[fj][r]);
      *(s16x4*)&Ps[wv][lr][fj * 16 + lg * 4] = pw;
    }

    // ---- PV (A-frag from Ps, V frags from L1/L2)
    const s16x8 pa0 = *(const s16x8*)&Ps[wv][lr][lg * 8];
    const s16x8 pa1 = *(const s16x8*)&Ps[wv][lr][32 + lg * 8];
#pragma unroll
    for (int fd = 0; fd < 4; ++fd) {
      const short* vrow = vT + bhoff + (size_t)(fd * 16 + lr) * SS + j0 + lg * 8;
      const s16x8 v0 = *(const s16x8*)vrow;
      const s16x8 v1 = *(const s16x8*)(vrow + 32);
      oacc[fd] = MFMA16(pa0, v0, oacc[fd]);
      oacc[fd] = MFMA16(pa1, v1, oacc[fd]);
    }
  }

  // ---- split-KV merge across the 8 waves (Om overlays Ps: barrier first)
  __syncthreads();
#pragma unroll
  for (int fd = 0; fd < 4; ++fd)
#pragma unroll
    for (int r = 0; r < 4; ++r)
      Om[wv][lg * 4 + r][fd * 16 + lr] = oacc[fd][r];
  if (lg == 0) { Mm[wv][lr] = mrow; Lm[wv][lr] = lrow; }
  __syncthreads();

  // waves 0-3 finalize (each one 16-col slice), summing over all 8 partials
  if (wv < 4) {
#pragma unroll
    for (int r = 0; r < 4; ++r) {
      const int il = lg * 4 + r;
      float mt = -1e30f;
#pragma unroll
      for (int w = 0; w < 8; ++w) mt = fmaxf(mt, Mm[w][il]);
      float L = 0.f, o = 0.f;
#pragma unroll
      for (int w = 0; w < 8; ++w) {
        const float sc = __expf(Mm[w][il] - mt);
        L += Lm[w][il] * sc;
        o += Om[w][il][wv * 16 + lr] * sc;
      }
      ao[((size_t)b * SS + i0 + il) * HIDN + h * DH + wv * 16 + lr] = f2bf(o / L);
    }
  }
}

// ---------------------------------------------------------------- launch
extern "C" void kernel_launch(void* const* d_in, const int* in_sizes, int n_in,
                              void* d_out, int out_size, void* d_ws, size_t ws_size,
                              hipStream_t stream) {
  const float* x   = (const float*)d_in[0];
  const int* mask  = (const int*)d_in[1];
  const float* Wq  = (const float*)d_in[2];  const float* bq  = (const float*)d_in[3];
  const float* Wk  = (const float*)d_in[4];  const float* bk  = (const float*)d_in[5];
  const float* Wv  = (const float*)d_in[6];  const float* bv  = (const float*)d_in[7];
  const float* Wo  = (const float*)d_in[8];  const float* bo  = (const float*)d_in[9];
  const float* rel = (const float*)d_in[10];
  const float* Wpk = (const float*)d_in[11]; const float* bpk = (const float*)d_in[12];
  const float* Wpq = (const float*)d_in[13]; const float* bpq = (const float*)d_in[14];
  const float* g1  = (const float*)d_in[15]; const float* be1 = (const float*)d_in[16];
  const float* g2  = (const float*)d_in[17]; const float* be2 = (const float*)d_in[18];
  const float* W1  = (const float*)d_in[19]; const float* bf1 = (const float*)d_in[20];
  const float* W2  = (const float*)d_in[21]; const float* bf2 = (const float*)d_in[22];
  float* out = (float*)d_out;

  char* ws = (char*)d_ws;
  const size_t MB = (size_t)1 << 20;
  // persistent
  short* aoB   = (short*)(ws + 0 * MB);    // 8 MB
  short* qhB   = (short*)(ws + 8 * MB);    // 8 MB
  short* khB   = (short*)(ws + 16 * MB);   // 8 MB
  short* vTB   = (short*)(ws + 24 * MB);   // 8 MB
  short* poskB = (short*)(ws + 32 * MB);   // 2 MB
  short* posqB = (short*)(ws + 34 * MB);   // 2 MB
  // stage 1-3 transient
  short* xn    = (short*)(ws + 36 * MB);   // 8 MB
  short* WqT   = (short*)(ws + 44 * MB);   // 2 MB  } contiguous 6 MB = fused QKV Bt
  short* WkT   = (short*)(ws + 46 * MB);   // 2 MB  }
  short* WvT   = (short*)(ws + 48 * MB);   // 2 MB  }
  short* WpkT  = (short*)(ws + 50 * MB);   // 2 MB  } contiguous 4 MB = fused pos Bt
  short* WpqT  = (short*)(ws + 52 * MB);   // 2 MB  }
  short* relbf = (short*)(ws + 54 * MB);   // 2 MB
  // stage 4 (HG=8)
  short* c2pG  = (short*)(ws + 36 * MB);   // 64 MB  [B, HG, S(i), 2K(cc)]
  short* p2cG  = (short*)(ws + 100 * MB);  // 64 MB  [B, HG, S(j), 2K(cp)]
  short* p2cE  = (short*)(ws + 164 * MB);  // 128 KB edge columns
  // stage 5
  short* WoT   = (short*)(ws + 36 * MB);   // 2 MB
  short* hnB   = (short*)(ws + 38 * MB);   // 8 MB
  short* W1T   = (short*)(ws + 46 * MB);   // 8 MB
  short* W2T   = (short*)(ws + 54 * MB);   // 8 MB
  short* midB  = (short*)(ws + 62 * MB);   // 32 MB
  (void)ws_size; (void)in_sizes; (void)n_in; (void)out_size;

  const int M = BB * SS;  // 4096

  // ---- stage 1: batched weight prep + LN
  TCBatch tc;
  tc.in[0] = Wq;  tc.out[0] = WqT;
  tc.in[1] = Wk;  tc.out[1] = WkT;
  tc.in[2] = Wv;  tc.out[2] = WvT;
  tc.in[3] = Wpk; tc.out[3] = WpkT;
  tc.in[4] = Wpq; tc.out[4] = WpqT;
  k_tcast5<<<dim3(32, 32, 5), 256, 0, stream>>>(tc);
  k_cast<<<1024, 256, 0, stream>>>(rel, relbf, 1024 * 1024 / 4);
  k_ln<<<M, 256, 0, stream>>>(x, g1, be1, xn);

  // ---- stage 2: fused projections
  k_gemm_qkv<<<dim3(24, 32), 256, 0, stream>>>(xn, WqT, bq, bk, bv, qhB, khB, vTB);
  k_gemm_pos<<<dim3(16, 8), 256, 0, stream>>>(relbf, WpkT, bpk, bpq, poskB, posqB);

  // ---- stage 4: attention in 2 head-groups of 8
  for (int g = 0; g < NHH / HG; ++g) {
    const int h0 = g * HG;
    k_posgemm<<<dim3(8, 16, 4 * HG), 256, 0, stream>>>(qhB, khB, poskB, posqB,
                                                       c2pG, p2cG, p2cE, h0);
    k_attn<<<BB * HG * 128, 512, DYN_LDS, stream>>>(qhB, khB, vTB, c2pG, p2cG, p2cE,
                                                    mask, aoB, h0);
  }

  // ---- stage 5
  k_tcast<<<dim3(32, 32), 256, 0, stream>>>(Wo, WoT, 1024, 1024);
  k_gemm<OM_RESID><<<dim3(8, 32), 256, 0, stream>>>(aoB, WoT, bo, x, out, M, 1024, 1024);
  k_ln<<<M, 256, 0, stream>>>(out, g2, be2, hnB);
  k_tcast<<<dim3(128, 32), 256, 0, stream>>>(W1, W1T, 1024, 4096);
  k_tcast<<<dim3(32, 128), 256, 0, stream>>>(W2, W2T, 4096, 1024);
  k_gemm<OM_GELU><<<dim3(32, 32), 256, 0, stream>>>(hnB, W1T, bf1, nullptr, midB, M, 4096, 1024);
  k_gemm<OM_RESID><<<dim3(8, 32), 256, 0, stream>>>(midB, W2T, bf2, out, out, M, 1024, 4096);
}